// Round 16
// baseline (135.074 us; speedup 1.0000x reference)
//
#include <hip/hip_runtime.h>
#include <hip/hip_bf16.h>

typedef __attribute__((ext_vector_type(8))) short bf16x8;
typedef __attribute__((ext_vector_type(4))) float f32x4;
typedef __attribute__((ext_vector_type(16))) float f32x16;

#define NTOK 50
#define CDIM 256
#define NH   8
#define LOG2E 1.4426950408889634f
#define QSCALE (0.17677669529663687f * 1.4426950408889634f)  // scale * log2e
#define MFMA32(a,b,c) __builtin_amdgcn_mfma_f32_32x32x16_bf16(a,b,c,0,0,0)
#define Z16 {0.f,0.f,0.f,0.f,0.f,0.f,0.f,0.f,0.f,0.f,0.f,0.f,0.f,0.f,0.f,0.f}

__device__ __forceinline__ unsigned short f2bf(float f) {
  union { __hip_bfloat16 h; unsigned short u; } c;
  c.h = __float2bfloat16(f);  // RNE
  return c.u;
}
__device__ __forceinline__ unsigned pk2(float a, float b) {
  return (unsigned)f2bf(a) | ((unsigned)f2bf(b) << 16);
}

// Exchange primitive (validated r1-r15): packed 32x32 C-tile -> MFMA A/B frag
// for axis chunk c1 (values c1*16 + myh*8 + j). 2 shfl + cndmasks.
__device__ __forceinline__ bf16x8 xchg(uint2 pkA, uint2 pkB, int myh) {
  unsigned ownx = myh ? pkB.x : pkA.x, owny = myh ? pkB.y : pkA.y;
  unsigned crx  = myh ? pkA.x : pkB.x, cry  = myh ? pkA.y : pkB.y;
  crx = (unsigned)__shfl_xor((int)crx, 32);
  cry = (unsigned)__shfl_xor((int)cry, 32);
  union { bf16x8 v; unsigned u[4]; } r;
  r.u[0] = myh ? crx : ownx;
  r.u[1] = myh ? cry : owny;
  r.u[2] = myh ? ownx : crx;
  r.u[3] = myh ? owny : cry;
  return r.v;
}

// Swizzled [tok][d] tile, 512 B row pitch (validated r2-r15: ~0 bank conflicts)
__device__ __forceinline__ bf16x8 ld_tile(const char* base, int row, int kc, int myh) {
  int byte = row * 512 + ((((kc << 1) | myh) ^ (row & 31)) << 4);
  return *(const bf16x8*)(base + byte);
}

// prep: W bf16 frag-ordered; Q pre-scaled by scale*log2e; biasT frag-ordered,
// x log2e, key-mask folded in. (validated r4-r15)
__global__ void prep_kernel(const float* __restrict__ qkv_w, const float* __restrict__ proj_w,
                            const float* __restrict__ bias_table, const int* __restrict__ rel_idx,
                            unsigned short* __restrict__ wq, unsigned short* __restrict__ wp,
                            float* __restrict__ biasT) {
  int i = blockIdx.x * 256 + (int)threadIdx.x;
  if (i < 768 * 256) {
    int row = i >> 8, col = i & 255;
    int mat = row >> 8, h = (row >> 5) & 7, r31 = row & 31;
    int kc = col >> 4, hh = (col >> 3) & 1, j = col & 7;
    int dst = ((((mat * 8 + h) * 16 + kc) * 2 + hh) * 32 + r31) * 8 + j;
    float v = qkv_w[i];
    if (mat == 0) v *= QSCALE;
    wq[dst] = f2bf(v);
  }
  if (i < 256 * 256) {
    int row = i >> 8, col = i & 255;
    int wv = row >> 5, r31 = row & 31;
    int kc = col >> 4, hh = (col >> 3) & 1, j = col & 7;
    int dst = (((wv * 16 + kc) * 2 + hh) * 32 + r31) * 8 + j;
    wp[dst] = f2bf(proj_w[i]);
  }
  if (i < 32768) {
    int h = i >> 12, kt = (i >> 11) & 1, qt = (i >> 10) & 1;
    int grp = (i >> 8) & 3, hh = (i >> 7) & 1, l31 = (i >> 2) & 31, rr = i & 3;
    int key = kt * 32 + grp * 8 + hh * 4 + rr;
    int query = qt * 32 + l31;
    float v;
    if (key >= NTOK) v = -1e30f;                               // padded keys -> exp2 underflow = 0
    else if (query == 0 || key == 0 || query >= NTOK) v = 0.f; // region token row/col
    else v = bias_table[rel_idx[(query - 1) * 49 + (key - 1)] * NH + h] * LOG2E;
    biasT[i] = v;
  }
}

// r16 = r15 skeleton + PER-HALF FUSED QKV: loop over token-half, one x-frag
// read feeds Q(swapped)+K(swapped)+V(normal) MFMAs. x LDS reads 96->32/wave
// (-64 ds_read_b128 + addr VALU); weights re-read per half (+48 L2 loads,
// latency hidden). Liveness half-1: 48 AGPR acc + 24 carried frags + ~24
// in-flight weights ~= 116 < 128 cap. Guard: WRITE_SIZE == 102400 KB.
__global__ __launch_bounds__(512, 4)
void mhsa_kernel(const float* __restrict__ x, const unsigned short* __restrict__ wq,
                 const unsigned short* __restrict__ wp, const float* __restrict__ biasT,
                 const float* __restrict__ qkv_b, const float* __restrict__ proj_b,
                 float* __restrict__ out) {
  __shared__ uint4 shbuf[4096];              // 64 KB
  char* xT = (char*)shbuf;                   // x : 64 x 512B swizzled
  char* oT = (char*)shbuf + 32768;           // O : 64 x 512B swizzled

  const int b = blockIdx.x;
  const int tid = (int)threadIdx.x;
  const int h = tid >> 6;                    // wave id = head
  const int lane = tid & 63;
  const int l31 = lane & 31;
  const int myh = lane >> 5;
  const int fragoff = myh * 256 + l31 * 8;

  // ---- stage x -> swizzled bf16 LDS (rows >= 50 zeroed) ----
  {
    const float* xb = x + (size_t)b * NTOK * CDIM;
    #pragma unroll 4
    for (int i = 0; i < 8; ++i) {
      int flat = i * 512 + tid;
      int row = flat >> 6, c4 = flat & 63;
      uint2 pv = make_uint2(0u, 0u);
      if (row < NTOK) {
        float4 v = *(const float4*)&xb[row * CDIM + c4 * 4];
        pv.x = pk2(v.x, v.y);
        pv.y = pk2(v.z, v.w);
      }
      int byte = row * 512 + ((((c4 >> 1) ^ (row & 31)) << 4) | ((c4 & 1) << 3));
      *(uint2*)(xT + byte) = pv;
    }
  }
  __syncthreads();

  const unsigned short* wQb = wq + (size_t)h * 8192;
  const unsigned short* wKb = wq + 65536 + (size_t)h * 8192;
  const unsigned short* wVb = wq + 131072 + (size_t)h * 8192;

  // ---- PER-HALF FUSED QKV: one x-frag read -> 3 MFMAs ----
  bf16x8 Qf[2][2], Kf[2][2], Vf[4];
  #pragma unroll
  for (int half = 0; half < 2; ++half) {
    f32x16 aQ, aK, aV;
    #pragma unroll
    for (int g = 0; g < 4; ++g) {
      f32x4 bq4 = *(const f32x4*)&qkv_b[h * 32 + 8 * g + 4 * myh];
      f32x4 bk4 = *(const f32x4*)&qkv_b[CDIM + h * 32 + 8 * g + 4 * myh];
      #pragma unroll
      for (int rr = 0; rr < 4; ++rr) {
        aQ[4*g+rr] = bq4[rr] * QSCALE;   // Q/K swapped: regs = d
        aK[4*g+rr] = bk4[rr];
      }
    }
    const float bv = qkv_b[2 * CDIM + h * 32 + l31];   // V normal: lane = d
    #pragma unroll
    for (int r = 0; r < 16; ++r) aV[r] = bv;

    #pragma unroll 2
    for (int kc = 0; kc < 16; ++kc) {
      bf16x8 xf = ld_tile(xT, half * 32 + l31, kc, myh);
      aQ = MFMA32(*(const bf16x8*)&wQb[kc * 512 + fragoff], xf, aQ);  // D[d][tok]
      aK = MFMA32(*(const bf16x8*)&wKb[kc * 512 + fragoff], xf, aK);  // D[d][tok]
      aV = MFMA32(xf, *(const bf16x8*)&wVb[kc * 512 + fragoff], aV);  // D[tok][d]
    }

    uint2 p[4];
    #pragma unroll
    for (int g = 0; g < 4; ++g)
      p[g] = make_uint2(pk2(aQ[4*g], aQ[4*g+1]), pk2(aQ[4*g+2], aQ[4*g+3]));
    Qf[half][0] = xchg(p[0], p[1], myh);  Qf[half][1] = xchg(p[2], p[3], myh);
    #pragma unroll
    for (int g = 0; g < 4; ++g)
      p[g] = make_uint2(pk2(aK[4*g], aK[4*g+1]), pk2(aK[4*g+2], aK[4*g+3]));
    Kf[half][0] = xchg(p[0], p[1], myh);  Kf[half][1] = xchg(p[2], p[3], myh);
    #pragma unroll
    for (int g = 0; g < 4; ++g)
      p[g] = make_uint2(pk2(aV[4*g], aV[4*g+1]), pk2(aV[4*g+2], aV[4*g+3]));
    Vf[2*half]   = xchg(p[0], p[1], myh);
    Vf[2*half+1] = xchg(p[2], p[3], myh);
  }

  // ---- attn per query-tile: S init from biasT -> MFMA -> max-free exp2 -> PV ----
  #pragma unroll
  for (int qt = 0; qt < 2; ++qt) {
    f32x16 s0, s1;
    {
      const float* bT0 = biasT + (size_t)(((h * 2 + 0) * 2 + qt) * 1024);
      const float* bT1 = biasT + (size_t)(((h * 2 + 1) * 2 + qt) * 1024);
      #pragma unroll
      for (int g = 0; g < 4; ++g) {
        f32x4 v0 = *(const f32x4*)&bT0[(g * 2 + myh) * 128 + l31 * 4];
        f32x4 v1 = *(const f32x4*)&bT1[(g * 2 + myh) * 128 + l31 * 4];
        #pragma unroll
        for (int rr = 0; rr < 4; ++rr) { s0[4*g+rr] = v0[rr]; s1[4*g+rr] = v1[rr]; }
      }
    }
    s0 = MFMA32(Kf[0][0], Qf[qt][0], s0);  s0 = MFMA32(Kf[0][1], Qf[qt][1], s0);
    s1 = MFMA32(Kf[1][0], Qf[qt][0], s1);  s1 = MFMA32(Kf[1][1], Qf[qt][1], s1);
    // max-free softmax (log2 domain): |S| <= ~14, exp2 overflow margin ~2^100;
    // masked keys (-1e30 bias) underflow to exactly 0.
    float sum = 0.f;
    #pragma unroll
    for (int r = 0; r < 16; ++r) {
      float e0 = __builtin_amdgcn_exp2f(s0[r]); s0[r] = e0; sum += e0;
      float e1 = __builtin_amdgcn_exp2f(s1[r]); s1[r] = e1; sum += e1;
    }
    sum += __shfl_xor(sum, 32);
    const float inv = 1.f / sum;
    f32x16 o = Z16;
    {
      uint2 pp[4];
      #pragma unroll
      for (int g = 0; g < 4; ++g)
        pp[g] = make_uint2(pk2(s0[4*g]*inv, s0[4*g+1]*inv), pk2(s0[4*g+2]*inv, s0[4*g+3]*inv));
      o = MFMA32(xchg(pp[0], pp[1], myh), Vf[0], o);
      o = MFMA32(xchg(pp[2], pp[3], myh), Vf[1], o);
      #pragma unroll
      for (int g = 0; g < 4; ++g)
        pp[g] = make_uint2(pk2(s1[4*g]*inv, s1[4*g+1]*inv), pk2(s1[4*g+2]*inv, s1[4*g+3]*inv));
      o = MFMA32(xchg(pp[0], pp[1], myh), Vf[2], o);
      o = MFMA32(xchg(pp[2], pp[3], myh), Vf[3], o);
    }
    // O (lane = d, regs = token) -> oT, scalar b16 (2-way free pattern)
    const int slotbase = (h << 2) | (l31 >> 3);
    #pragma unroll
    for (int r = 0; r < 16; ++r) {
      int t = qt * 32 + (r & 3) + 8 * (r >> 2) + 4 * myh;
      int byte = t * 512 + (((slotbase ^ (t & 31)) << 4) | ((l31 & 7) << 1));
      *(unsigned short*)(oT + byte) = f2bf(o[r]);
    }
  }

  __syncthreads();   // O complete across all waves

  // ---- proj: out = O * Wp^T + pb; wave owns e-cols [32h, 32h+32) ----
  {
    const unsigned short* wPb = wp + (size_t)h * 8192;
    f32x16 po0, po1;
    const float pb = proj_b[h * 32 + l31];
    #pragma unroll
    for (int r = 0; r < 16; ++r) { po0[r] = pb; po1[r] = pb; }
    #pragma unroll 2
    for (int kc = 0; kc < 16; ++kc) {
      bf16x8 wpf = *(const bf16x8*)&wPb[kc * 512 + fragoff];
      po0 = MFMA32(ld_tile(oT, l31, kc, myh), wpf, po0);
      po1 = MFMA32(ld_tile(oT, 32 + l31, kc, myh), wpf, po1);
    }
    #pragma unroll
    for (int r = 0; r < 16; ++r) {
      int t0 = (r & 3) + 8 * (r >> 2) + 4 * myh;
      if (t0 < NTOK) out[((size_t)b * NTOK + t0) * CDIM + h * 32 + l31] = po0[r];
      int t1 = 32 + t0;
      if (t1 < NTOK) out[((size_t)b * NTOK + t1) * CDIM + h * 32 + l31] = po1[r];
    }
  }
}

extern "C" void kernel_launch(void* const* d_in, const int* in_sizes, int n_in,
                              void* d_out, int out_size, void* d_ws, size_t ws_size,
                              hipStream_t stream) {
  const float* x          = (const float*)d_in[0];
  const float* qkv_w      = (const float*)d_in[1];
  const float* qkv_b      = (const float*)d_in[2];
  const float* proj_w     = (const float*)d_in[3];
  const float* proj_b     = (const float*)d_in[4];
  const float* bias_table = (const float*)d_in[5];
  const int*   rel_idx    = (const int*)d_in[6];

  unsigned short* wq = (unsigned short*)d_ws;          // 768*256 bf16, frag-ordered
  unsigned short* wp = wq + 768 * 256;                 // 256*256 bf16, frag-ordered
  float* biasT = (float*)(wp + 256 * 256);             // 32768 f32, frag-ordered, log2-domain

  prep_kernel<<<768, 256, 0, stream>>>(qkv_w, proj_w, bias_table, rel_idx, wq, wp, biasT);
  mhsa_kernel<<<2048, 512, 0, stream>>>(x, wq, wp, biasT, qkv_b, proj_b, (float*)d_out);
}

// Round 17
// 126.971 us; speedup vs baseline: 1.0638x; 1.0638x over previous
//
#include <hip/hip_runtime.h>
#include <hip/hip_bf16.h>

typedef __attribute__((ext_vector_type(8))) short bf16x8;
typedef __attribute__((ext_vector_type(4))) float f32x4;
typedef __attribute__((ext_vector_type(16))) float f32x16;

#define NTOK 50
#define CDIM 256
#define NH   8
#define LOG2E 1.4426950408889634f
#define QSCALE (0.17677669529663687f * 1.4426950408889634f)  // scale * log2e
#define MFMA32(a,b,c) __builtin_amdgcn_mfma_f32_32x32x16_bf16(a,b,c,0,0,0)
#define Z16 {0.f,0.f,0.f,0.f,0.f,0.f,0.f,0.f,0.f,0.f,0.f,0.f,0.f,0.f,0.f,0.f}

__device__ __forceinline__ unsigned short f2bf(float f) {
  union { __hip_bfloat16 h; unsigned short u; } c;
  c.h = __float2bfloat16(f);  // RNE
  return c.u;
}
__device__ __forceinline__ unsigned pk2(float a, float b) {
  return (unsigned)f2bf(a) | ((unsigned)f2bf(b) << 16);
}

// Exchange primitive (validated r1-r16: absmax 0.0117): packed 32x32 C-tile ->
// MFMA A/B frag for axis chunk c1 (values c1*16 + myh*8 + j). 2 shfl + cndmasks.
__device__ __forceinline__ bf16x8 xchg(uint2 pkA, uint2 pkB, int myh) {
  unsigned ownx = myh ? pkB.x : pkA.x, owny = myh ? pkB.y : pkA.y;
  unsigned crx  = myh ? pkA.x : pkB.x, cry  = myh ? pkA.y : pkB.y;
  crx = (unsigned)__shfl_xor((int)crx, 32);
  cry = (unsigned)__shfl_xor((int)cry, 32);
  union { bf16x8 v; unsigned u[4]; } r;
  r.u[0] = myh ? crx : ownx;
  r.u[1] = myh ? cry : owny;
  r.u[2] = myh ? ownx : crx;
  r.u[3] = myh ? owny : cry;
  return r.v;
}

// Swizzled [tok][d] tile, 512 B row pitch (validated r2-r16: ~0 bank conflicts)
__device__ __forceinline__ bf16x8 ld_tile(const char* base, int row, int kc, int myh) {
  int byte = row * 512 + ((((kc << 1) | myh) ^ (row & 31)) << 4);
  return *(const bf16x8*)(base + byte);
}

// prep: W bf16 frag-ordered; Q pre-scaled by scale*log2e; biasT frag-ordered,
// x log2e, key-mask folded in. (validated r4-r16)
__global__ void prep_kernel(const float* __restrict__ qkv_w, const float* __restrict__ proj_w,
                            const float* __restrict__ bias_table, const int* __restrict__ rel_idx,
                            unsigned short* __restrict__ wq, unsigned short* __restrict__ wp,
                            float* __restrict__ biasT) {
  int i = blockIdx.x * 256 + (int)threadIdx.x;
  if (i < 768 * 256) {
    int row = i >> 8, col = i & 255;
    int mat = row >> 8, h = (row >> 5) & 7, r31 = row & 31;
    int kc = col >> 4, hh = (col >> 3) & 1, j = col & 7;
    int dst = ((((mat * 8 + h) * 16 + kc) * 2 + hh) * 32 + r31) * 8 + j;
    float v = qkv_w[i];
    if (mat == 0) v *= QSCALE;
    wq[dst] = f2bf(v);
  }
  if (i < 256 * 256) {
    int row = i >> 8, col = i & 255;
    int wv = row >> 5, r31 = row & 31;
    int kc = col >> 4, hh = (col >> 3) & 1, j = col & 7;
    int dst = (((wv * 16 + kc) * 2 + hh) * 32 + r31) * 8 + j;
    wp[dst] = f2bf(proj_w[i]);
  }
  if (i < 32768) {
    int h = i >> 12, kt = (i >> 11) & 1, qt = (i >> 10) & 1;
    int grp = (i >> 8) & 3, hh = (i >> 7) & 1, l31 = (i >> 2) & 31, rr = i & 3;
    int key = kt * 32 + grp * 8 + hh * 4 + rr;
    int query = qt * 32 + l31;
    float v;
    if (key >= NTOK) v = -1e30f;                               // padded keys: softmax mask
    else if (query == 0 || key == 0 || query >= NTOK) v = 0.f; // region token row/col
    else v = bias_table[rel_idx[(query - 1) * 49 + (key - 1)] * NH + h] * LOG2E;
    biasT[i] = v;
  }
}

// FINAL (r13 optimum, 127 us, zero spill): free-running wave design. 512 thr /
// 8 waves, wave = head, whole pipeline x->Q/K/V->attn->O register-resident per
// wave; sequential QKV loops (32-AGPR acc max), unroll 2 (spill control),
// bias-init accumulators incl. S-from-biasT, log2-domain softmax. 128-reg cap
// of (512,4) -> 2 independent blocks/CU = 16 waves/CU. LDS 64 KB (x + separate
// O) -> only TWO barriers; waves de-synchronize through QKV+attn.
// Plateau: r5/r12/r14/r15/r16 perturbations all neutral-or-negative; binding
// constraint is per-wave dependency latency x the 128-reg concurrency cap.
__global__ __launch_bounds__(512, 4)
void mhsa_kernel(const float* __restrict__ x, const unsigned short* __restrict__ wq,
                 const unsigned short* __restrict__ wp, const float* __restrict__ biasT,
                 const float* __restrict__ qkv_b, const float* __restrict__ proj_b,
                 float* __restrict__ out) {
  __shared__ uint4 shbuf[4096];              // 64 KB
  char* xT = (char*)shbuf;                   // x : 64 x 512B swizzled
  char* oT = (char*)shbuf + 32768;           // O : 64 x 512B swizzled

  const int b = blockIdx.x;
  const int tid = (int)threadIdx.x;
  const int h = tid >> 6;                    // wave id = head
  const int lane = tid & 63;
  const int l31 = lane & 31;
  const int myh = lane >> 5;
  const int fragoff = myh * 256 + l31 * 8;

  // ---- stage x -> swizzled bf16 LDS (rows >= 50 zeroed) ----
  {
    const float* xb = x + (size_t)b * NTOK * CDIM;
    #pragma unroll 4
    for (int i = 0; i < 8; ++i) {
      int flat = i * 512 + tid;
      int row = flat >> 6, c4 = flat & 63;
      uint2 pv = make_uint2(0u, 0u);
      if (row < NTOK) {
        float4 v = *(const float4*)&xb[row * CDIM + c4 * 4];
        pv.x = pk2(v.x, v.y);
        pv.y = pk2(v.z, v.w);
      }
      int byte = row * 512 + ((((c4 >> 1) ^ (row & 31)) << 4) | ((c4 & 1) << 3));
      *(uint2*)(xT + byte) = pv;
    }
  }
  __syncthreads();

  const unsigned short* wQb = wq + (size_t)h * 8192;
  const unsigned short* wKb = wq + 65536 + (size_t)h * 8192;
  const unsigned short* wVb = wq + 131072 + (size_t)h * 8192;

  // ---- Q GEMM (swapped: D[d-regs][tok-lane]), bias-init acc, 2 acc tiles ----
  bf16x8 Qf[2][2], Kf[2][2], Vf[4];
  {
    f32x16 a0, a1;
    #pragma unroll
    for (int g = 0; g < 4; ++g) {
      f32x4 b4 = *(const f32x4*)&qkv_b[h * 32 + 8 * g + 4 * myh];
      #pragma unroll
      for (int rr = 0; rr < 4; ++rr) { a0[4*g+rr] = b4[rr] * QSCALE; a1[4*g+rr] = b4[rr] * QSCALE; }
    }
    #pragma unroll 2
    for (int kc = 0; kc < 16; ++kc) {
      bf16x8 wf = *(const bf16x8*)&wQb[kc * 512 + fragoff];
      a0 = MFMA32(wf, ld_tile(xT, l31, kc, myh), a0);
      a1 = MFMA32(wf, ld_tile(xT, 32 + l31, kc, myh), a1);
    }
    uint2 p[4];
    #pragma unroll
    for (int g = 0; g < 4; ++g)
      p[g] = make_uint2(pk2(a0[4*g], a0[4*g+1]), pk2(a0[4*g+2], a0[4*g+3]));
    Qf[0][0] = xchg(p[0], p[1], myh);  Qf[0][1] = xchg(p[2], p[3], myh);
    #pragma unroll
    for (int g = 0; g < 4; ++g)
      p[g] = make_uint2(pk2(a1[4*g], a1[4*g+1]), pk2(a1[4*g+2], a1[4*g+3]));
    Qf[1][0] = xchg(p[0], p[1], myh);  Qf[1][1] = xchg(p[2], p[3], myh);
  }
  // ---- K GEMM (same shape, no scale) ----
  {
    f32x16 a0, a1;
    #pragma unroll
    for (int g = 0; g < 4; ++g) {
      f32x4 b4 = *(const f32x4*)&qkv_b[CDIM + h * 32 + 8 * g + 4 * myh];
      #pragma unroll
      for (int rr = 0; rr < 4; ++rr) { a0[4*g+rr] = b4[rr]; a1[4*g+rr] = b4[rr]; }
    }
    #pragma unroll 2
    for (int kc = 0; kc < 16; ++kc) {
      bf16x8 wf = *(const bf16x8*)&wKb[kc * 512 + fragoff];
      a0 = MFMA32(wf, ld_tile(xT, l31, kc, myh), a0);
      a1 = MFMA32(wf, ld_tile(xT, 32 + l31, kc, myh), a1);
    }
    uint2 p[4];
    #pragma unroll
    for (int g = 0; g < 4; ++g)
      p[g] = make_uint2(pk2(a0[4*g], a0[4*g+1]), pk2(a0[4*g+2], a0[4*g+3]));
    Kf[0][0] = xchg(p[0], p[1], myh);  Kf[0][1] = xchg(p[2], p[3], myh);
    #pragma unroll
    for (int g = 0; g < 4; ++g)
      p[g] = make_uint2(pk2(a1[4*g], a1[4*g+1]), pk2(a1[4*g+2], a1[4*g+3]));
    Kf[1][0] = xchg(p[0], p[1], myh);  Kf[1][1] = xchg(p[2], p[3], myh);
  }
  // ---- V GEMM (normal: D[tok-regs][d-lane]) ----
  {
    f32x16 a0, a1;
    const float bv = qkv_b[2 * CDIM + h * 32 + l31];
    #pragma unroll
    for (int r = 0; r < 16; ++r) { a0[r] = bv; a1[r] = bv; }
    #pragma unroll 2
    for (int kc = 0; kc < 16; ++kc) {
      bf16x8 wf = *(const bf16x8*)&wVb[kc * 512 + fragoff];
      a0 = MFMA32(ld_tile(xT, l31, kc, myh), wf, a0);
      a1 = MFMA32(ld_tile(xT, 32 + l31, kc, myh), wf, a1);
    }
    uint2 p[4];
    #pragma unroll
    for (int g = 0; g < 4; ++g)
      p[g] = make_uint2(pk2(a0[4*g], a0[4*g+1]), pk2(a0[4*g+2], a0[4*g+3]));
    Vf[0] = xchg(p[0], p[1], myh);  Vf[1] = xchg(p[2], p[3], myh);
    #pragma unroll
    for (int g = 0; g < 4; ++g)
      p[g] = make_uint2(pk2(a1[4*g], a1[4*g+1]), pk2(a1[4*g+2], a1[4*g+3]));
    Vf[2] = xchg(p[0], p[1], myh);  Vf[3] = xchg(p[2], p[3], myh);
  }

  // ---- attn per query-tile: S init from biasT -> MFMA -> log2 softmax -> PV ----
  #pragma unroll
  for (int qt = 0; qt < 2; ++qt) {
    f32x16 s0, s1;
    {
      const float* bT0 = biasT + (size_t)(((h * 2 + 0) * 2 + qt) * 1024);
      const float* bT1 = biasT + (size_t)(((h * 2 + 1) * 2 + qt) * 1024);
      #pragma unroll
      for (int g = 0; g < 4; ++g) {
        f32x4 v0 = *(const f32x4*)&bT0[(g * 2 + myh) * 128 + l31 * 4];
        f32x4 v1 = *(const f32x4*)&bT1[(g * 2 + myh) * 128 + l31 * 4];
        #pragma unroll
        for (int rr = 0; rr < 4; ++rr) { s0[4*g+rr] = v0[rr]; s1[4*g+rr] = v1[rr]; }
      }
    }
    s0 = MFMA32(Kf[0][0], Qf[qt][0], s0);  s0 = MFMA32(Kf[0][1], Qf[qt][1], s0);
    s1 = MFMA32(Kf[1][0], Qf[qt][0], s1);  s1 = MFMA32(Kf[1][1], Qf[qt][1], s1);
    // softmax over 64 keys (log2 domain): 32 lane-local + one cross-half shfl
    float mx = -3e38f;
    #pragma unroll
    for (int r = 0; r < 16; ++r) { mx = fmaxf(mx, s0[r]); mx = fmaxf(mx, s1[r]); }
    mx = fmaxf(mx, __shfl_xor(mx, 32));
    float sum = 0.f;
    #pragma unroll
    for (int r = 0; r < 16; ++r) {
      float e0 = __builtin_amdgcn_exp2f(s0[r] - mx); s0[r] = e0; sum += e0;
      float e1 = __builtin_amdgcn_exp2f(s1[r] - mx); s1[r] = e1; sum += e1;
    }
    sum += __shfl_xor(sum, 32);
    const float inv = 1.f / sum;
    f32x16 o = Z16;
    {
      uint2 pp[4];
      #pragma unroll
      for (int g = 0; g < 4; ++g)
        pp[g] = make_uint2(pk2(s0[4*g]*inv, s0[4*g+1]*inv), pk2(s0[4*g+2]*inv, s0[4*g+3]*inv));
      o = MFMA32(xchg(pp[0], pp[1], myh), Vf[0], o);
      o = MFMA32(xchg(pp[2], pp[3], myh), Vf[1], o);
      #pragma unroll
      for (int g = 0; g < 4; ++g)
        pp[g] = make_uint2(pk2(s1[4*g]*inv, s1[4*g+1]*inv), pk2(s1[4*g+2]*inv, s1[4*g+3]*inv));
      o = MFMA32(xchg(pp[0], pp[1], myh), Vf[2], o);
      o = MFMA32(xchg(pp[2], pp[3], myh), Vf[3], o);
    }
    // O (lane = d, regs = token) -> oT immediately, scalar b16 (2-way free);
    // region (rows qt*32.., cols h*32..) is wave-private -> no barrier needed.
    const int slotbase = (h << 2) | (l31 >> 3);
    #pragma unroll
    for (int r = 0; r < 16; ++r) {
      int t = qt * 32 + (r & 3) + 8 * (r >> 2) + 4 * myh;
      int byte = t * 512 + (((slotbase ^ (t & 31)) << 4) | ((l31 & 7) << 1));
      *(unsigned short*)(oT + byte) = f2bf(o[r]);
    }
  }

  __syncthreads();   // O complete across all waves

  // ---- proj: out = O * Wp^T + pb; wave owns e-cols [32h, 32h+32) ----
  {
    const unsigned short* wPb = wp + (size_t)h * 8192;
    f32x16 po0, po1;
    const float pb = proj_b[h * 32 + l31];
    #pragma unroll
    for (int r = 0; r < 16; ++r) { po0[r] = pb; po1[r] = pb; }
    #pragma unroll 2
    for (int kc = 0; kc < 16; ++kc) {
      bf16x8 wpf = *(const bf16x8*)&wPb[kc * 512 + fragoff];
      po0 = MFMA32(ld_tile(oT, l31, kc, myh), wpf, po0);
      po1 = MFMA32(ld_tile(oT, 32 + l31, kc, myh), wpf, po1);
    }
    #pragma unroll
    for (int r = 0; r < 16; ++r) {
      int t0 = (r & 3) + 8 * (r >> 2) + 4 * myh;
      if (t0 < NTOK) out[((size_t)b * NTOK + t0) * CDIM + h * 32 + l31] = po0[r];
      int t1 = 32 + t0;
      if (t1 < NTOK) out[((size_t)b * NTOK + t1) * CDIM + h * 32 + l31] = po1[r];
    }
  }
}

extern "C" void kernel_launch(void* const* d_in, const int* in_sizes, int n_in,
                              void* d_out, int out_size, void* d_ws, size_t ws_size,
                              hipStream_t stream) {
  const float* x          = (const float*)d_in[0];
  const float* qkv_w      = (const float*)d_in[1];
  const float* qkv_b      = (const float*)d_in[2];
  const float* proj_w     = (const float*)d_in[3];
  const float* proj_b     = (const float*)d_in[4];
  const float* bias_table = (const float*)d_in[5];
  const int*   rel_idx    = (const int*)d_in[6];

  unsigned short* wq = (unsigned short*)d_ws;          // 768*256 bf16, frag-ordered
  unsigned short* wp = wq + 768 * 256;                 // 256*256 bf16, frag-ordered
  float* biasT = (float*)(wp + 256 * 256);             // 32768 f32, frag-ordered, log2-domain

  prep_kernel<<<768, 256, 0, stream>>>(qkv_w, proj_w, bias_table, rel_idx, wq, wp, biasT);
  mhsa_kernel<<<2048, 512, 0, stream>>>(x, wq, wp, biasT, qkv_b, proj_b, (float*)d_out);
}